// Round 12
// baseline (158.331 us; speedup 1.0000x reference)
//
#include <hip/hip_runtime.h>

typedef _Float16 h16;
typedef __attribute__((ext_vector_type(4))) _Float16 half4;
typedef __attribute__((ext_vector_type(8))) _Float16 half8;
typedef __attribute__((ext_vector_type(8))) float float8;

#define RANGES 8
#define PPR    64            // chunks per range for hist/fill -> 512 blocks
#define HTHREADS 1024
#define BINS   6400          // nodes per range: 8*6400 = 51200 >= 50000
#define HALF   (BINS / 2)    // packed words per histogram (odeg or ideg)
#define HWORDS (BINS)        // words per partial: HALF odeg + HALF ideg
#define NSEG   100           // 512-node scan segments (51200/512)
#define NFILL  (RANGES * PPR)
#define NBUCK  512           // bucket-pass blocks

// ======== bucket pass: one edge scan -> 8 dst-range buckets (u32) + 8 src-range buckets (u16)
// dbucket[r*E + i] = (dst_local << 16) | src_global ;  sbucket[r*E + i] = src_local
__global__ __launch_bounds__(HTHREADS) void bucket_kernel(
    const int* __restrict__ src, const int* __restrict__ dst,
    unsigned int* __restrict__ dbucket, unsigned short* __restrict__ sbucket,
    int* __restrict__ gcur, int E) {
  __shared__ int cnt[16];
  __shared__ int basep[16];
  const int tid = threadIdx.x;
  const int chunk = (E + NBUCK - 1) / NBUCK;
  const int e0 = blockIdx.x * chunk;
  const int e1 = min(E, e0 + chunk);
  for (int base = e0; base < e1; base += HTHREADS) {
    const int e = base + tid;
    const bool valid = e < e1;
    if (tid < 16) cnt[tid] = 0;
    __syncthreads();
    int s = 0, d = 0, kd = 0, ks = 0, offd = 0, offs = 0;
    if (valid) {
      s = src[e]; d = dst[e];
      kd = d / BINS;            // 0..7
      ks = 8 + s / BINS;        // 8..15
      offd = atomicAdd(&cnt[kd], 1);
      offs = atomicAdd(&cnt[ks], 1);
    }
    __syncthreads();
    if (tid < 16) basep[tid] = atomicAdd(&gcur[tid], cnt[tid]);
    __syncthreads();
    if (valid) {
      const int dl = d - kd * BINS;
      dbucket[(size_t)kd * E + basep[kd] + offd] = ((unsigned)dl << 16) | (unsigned)s;
      const int sl = s - (ks - 8) * BINS;
      sbucket[(size_t)(ks - 8) * E + basep[ks] + offs] = (unsigned short)sl;
    }
  }
}

// ======== histogram from buckets: 16-bit-packed LDS counters, per-(range,chunk) partials ====
__global__ __launch_bounds__(HTHREADS) void hist_kernel(
    const unsigned int* __restrict__ dbucket, const unsigned short* __restrict__ sbucket,
    const int* __restrict__ gcur, int* __restrict__ partial, int E) {
  __shared__ int h[HWORDS];  // 25.6 KB
  const int r = blockIdx.x >> 6;   // range
  const int c = blockIdx.x & 63;   // chunk
  for (int i = threadIdx.x; i < HWORDS; i += HTHREADS) h[i] = 0;
  __syncthreads();
  // odeg from src bucket r
  {
    const int L = gcur[8 + r];
    const int cs = (L + PPR - 1) / PPR;
    const int i0 = c * cs, i1 = min(L, i0 + cs);
    const unsigned short* sb = sbucket + (size_t)r * E;
    for (int i = i0 + threadIdx.x; i < i1; i += HTHREADS) {
      int sl = sb[i];
      atomicAdd(&h[sl >> 1], 1 << ((sl & 1) * 16));
    }
  }
  // ideg from dst bucket r
  {
    const int L = gcur[r];
    const int cs = (L + PPR - 1) / PPR;
    const int i0 = c * cs, i1 = min(L, i0 + cs);
    const unsigned int* db = dbucket + (size_t)r * E;
    for (int i = i0 + threadIdx.x; i < i1; i += HTHREADS) {
      int dl = db[i] >> 16;
      atomicAdd(&h[HALF + (dl >> 1)], 1 << ((dl & 1) * 16));
    }
  }
  __syncthreads();
  int* op = partial + (size_t)blockIdx.x * HWORDS;
  for (int i = threadIdx.x; i < HWORDS; i += HTHREADS) op[i] = h[i];
}

// ======== reduce partials -> norms; in-place chunk-prefix; 512-node segment scan ========
__global__ __launch_bounds__(256) void reduce_norm_scan1(
    int* __restrict__ partial, float* __restrict__ nout, float* __restrict__ nin,
    int* __restrict__ rowptr, int* __restrict__ bsums, int N) {
  __shared__ int s[256];
  const int j = blockIdx.x * 256 + threadIdx.x;    // packed word id, < 25600
  const int r = j / HALF;
  const int w = j % HALF;
  int* base = partial + (size_t)(r * PPR) * HWORDS;
  int sumO = 0, runI = 0;
#pragma unroll 8
  for (int p = 0; p < PPR; ++p) {
    sumO += base[(size_t)p * HWORDS + w];
    int vI = base[(size_t)p * HWORDS + HALF + w];
    base[(size_t)p * HWORDS + HALF + w] = runI;    // exclusive chunk-prefix (packed; no carry)
    runI += vI;
  }
  const int od0 = sumO & 0xFFFF, od1 = (sumO >> 16) & 0xFFFF;
  const int id0 = runI & 0xFFFF, id1 = (runI >> 16) & 0xFFFF;
  const int n0 = 2 * j, n1 = n0 + 1;
  if (n0 < N) {
    nout[n0] = od0 > 0 ? rsqrtf((float)od0) : 0.f;
    nin[n0]  = id0 > 0 ? rsqrtf((float)id0) : 0.f;
  }
  if (n1 < N) {
    nout[n1] = od1 > 0 ? rsqrtf((float)od1) : 0.f;
    nin[n1]  = id1 > 0 ? rsqrtf((float)id1) : 0.f;
  }
  const int local = id0 + id1;
  int v = local;
  s[threadIdx.x] = v;
  __syncthreads();
#pragma unroll
  for (int off = 1; off < 256; off <<= 1) {
    int tv = 0;
    if (threadIdx.x >= off) tv = s[threadIdx.x - off];
    __syncthreads();
    if (threadIdx.x >= off) s[threadIdx.x] += tv;
    __syncthreads();
  }
  const int excl = s[threadIdx.x] - v;              // segment-local exclusive start
  if (n0 < N) rowptr[n0] = excl;
  if (n1 < N) rowptr[n1] = excl + id0;
  if (threadIdx.x == 255) bsums[blockIdx.x] = s[255];
}

// ======== heterogeneous: blocks [0,512) CSR-fill from dst buckets; blocks [512,..) gemm1 ====
__global__ __launch_bounds__(HTHREADS) void fill_gemm_kernel(
    const unsigned int* __restrict__ dbucket, const int* __restrict__ gcur,
    const int* __restrict__ rowptr, const int* __restrict__ bsums,
    const int* __restrict__ partial, int* __restrict__ rowptr_abs,
    unsigned short* __restrict__ csr,
    const float* __restrict__ feat, const float* __restrict__ W1,
    const float* __restrict__ nout, half4* __restrict__ bufAh,
    int N, int E) {
  __shared__ __align__(16) char smem[51200];
  const int tid = threadIdx.x;

  if (blockIdx.x < NFILL) {
    // ---------------- fill ----------------
    int* cur = (int*)smem;                  // [BINS] absolute cursors (25.6 KB)
    int* top = (int*)(smem + BINS * 4);     // [128] scanned segment sums
    const int r = blockIdx.x & 7;    // range -> XCD (bid%8 round-robin)
    const int c = blockIdx.x >> 3;   // chunk 0..63
    if (tid < 128) top[tid] = (tid < NSEG) ? bsums[tid] : 0;
    __syncthreads();
#pragma unroll
    for (int off = 1; off < 128; off <<= 1) {
      int v = 0;
      if (tid < 128 && tid >= off) v = top[tid - off];
      __syncthreads();
      if (tid < 128 && tid >= off) top[tid] += v;
      __syncthreads();
    }
    const int lo = r * BINS;
    const int* pf = partial + (size_t)(r * PPR + c) * HWORDS + HALF;
    for (int n = tid; n < BINS; n += HTHREADS) {
      int g = lo + n;
      int rp = 0;
      if (g < N) {
        int seg = g >> 9;
        rp = rowptr[g] + (seg ? top[seg - 1] : 0);     // absolute row start
        if (c == 0) rowptr_abs[g] = rp;
      }
      int pw = pf[n >> 1];
      cur[n] = rp + ((pw >> ((n & 1) * 16)) & 0xFFFF);
    }
    if (blockIdx.x == 0 && tid == 0) rowptr_abs[N] = E;
    __syncthreads();
    const int L = gcur[r];
    const int cs = (L + PPR - 1) / PPR;
    const int i0 = c * cs, i1 = min(L, i0 + cs);
    const unsigned int* db = dbucket + (size_t)r * E;
    for (int i = i0 + tid; i < i1; i += HTHREADS) {
      unsigned int w = db[i];
      int pos = atomicAdd(&cur[w >> 16], 1);
      csr[pos] = (unsigned short)(w & 0xFFFF);
    }
  } else {
    // ---------------- gemm1 (128-row tile, 1024 threads) ----------------
    float* sA = (float*)smem;                   // [128][68]
    float* sB = (float*)(smem + 128 * 68 * 4);  // [64][64]
    const int tile = blockIdx.x - NFILL;
    const int row0 = tile << 7;
    const int ry = tid >> 4;                // 0..63 -> rows 2ry, 2ry+1
    const int tx = tid & 15;
    const int r0 = 2 * ry, r1 = r0 + 1;
    float4 acc0 = make_float4(0.f, 0.f, 0.f, 0.f);
    float4 acc1 = make_float4(0.f, 0.f, 0.f, 0.f);
#pragma unroll
    for (int kc = 0; kc < 2; ++kc) {
      __syncthreads();
      for (int i = tid * 4; i < 128 * 64; i += HTHREADS * 4) {
        int rr = i >> 6, cc = i & 63;
        int gr = row0 + rr;
        float4 v = make_float4(0.f, 0.f, 0.f, 0.f);
        if (gr < N) v = *reinterpret_cast<const float4*>(feat + (size_t)gr * 128 + kc * 64 + cc);
        *reinterpret_cast<float4*>(sA + rr * 68 + cc) = v;
      }
      {
        int i = tid * 4;
        int rr = i >> 6, cc = i & 63;
        *reinterpret_cast<float4*>(sB + rr * 64 + cc) =
            *reinterpret_cast<const float4*>(W1 + (size_t)(kc * 64 + rr) * 64 + cc);
      }
      __syncthreads();
#pragma unroll 8
      for (int k = 0; k < 64; ++k) {
        float a0 = sA[r0 * 68 + k], a1 = sA[r1 * 68 + k];
        float4 b = *reinterpret_cast<float4*>(sB + k * 64 + tx * 4);
        acc0.x += a0 * b.x; acc0.y += a0 * b.y; acc0.z += a0 * b.z; acc0.w += a0 * b.w;
        acc1.x += a1 * b.x; acc1.y += a1 * b.y; acc1.z += a1 * b.z; acc1.w += a1 * b.w;
      }
    }
#pragma unroll
    for (int rr = 0; rr < 2; ++rr) {
      const int gr = row0 + (rr ? r1 : r0);
      if (gr >= N) continue;
      float4 v = rr ? acc1 : acc0;
      float no = nout[gr];
      half4 hv;
      hv.x = (h16)(v.x * no); hv.y = (h16)(v.y * no);
      hv.z = (h16)(v.z * no); hv.w = (h16)(v.w * no);
      bufAh[(size_t)gr * 16 + tx] = hv;
    }
  }
}

// ======== shared gather core: 8 lanes/node, half8 (16B) loads, 8-way MLP unroll ========
__device__ __forceinline__ float8 gather_row(const int* __restrict__ rowptr,
                                             const unsigned short* __restrict__ csr,
                                             const half8* __restrict__ xv,
                                             int node, int lane) {
  const int b = rowptr[node], e = rowptr[node + 1];
  float8 a0 = 0.f, a1 = 0.f, a2 = 0.f, a3 = 0.f;
  int i = b;
  for (; i + 8 <= e; i += 8) {
    int s0 = csr[i + 0], s1 = csr[i + 1], s2 = csr[i + 2], s3 = csr[i + 3];
    int s4 = csr[i + 4], s5 = csr[i + 5], s6 = csr[i + 6], s7 = csr[i + 7];
    half8 v0 = xv[(size_t)s0 * 8 + lane];
    half8 v1 = xv[(size_t)s1 * 8 + lane];
    half8 v2 = xv[(size_t)s2 * 8 + lane];
    half8 v3 = xv[(size_t)s3 * 8 + lane];
    half8 v4 = xv[(size_t)s4 * 8 + lane];
    half8 v5 = xv[(size_t)s5 * 8 + lane];
    half8 v6 = xv[(size_t)s6 * 8 + lane];
    half8 v7 = xv[(size_t)s7 * 8 + lane];
#pragma unroll
    for (int j = 0; j < 8; ++j) {
      a0[j] += (float)v0[j]; a1[j] += (float)v1[j];
      a2[j] += (float)v2[j]; a3[j] += (float)v3[j];
      a0[j] += (float)v4[j]; a1[j] += (float)v5[j];
      a2[j] += (float)v6[j]; a3[j] += (float)v7[j];
    }
  }
  for (; i + 4 <= e; i += 4) {
    int s0 = csr[i + 0], s1 = csr[i + 1], s2 = csr[i + 2], s3 = csr[i + 3];
    half8 v0 = xv[(size_t)s0 * 8 + lane];
    half8 v1 = xv[(size_t)s1 * 8 + lane];
    half8 v2 = xv[(size_t)s2 * 8 + lane];
    half8 v3 = xv[(size_t)s3 * 8 + lane];
#pragma unroll
    for (int j = 0; j < 8; ++j) {
      a0[j] += (float)v0[j]; a1[j] += (float)v1[j];
      a2[j] += (float)v2[j]; a3[j] += (float)v3[j];
    }
  }
  for (; i < e; ++i) {
    int s = csr[i];
    half8 v = xv[(size_t)s * 8 + lane];
#pragma unroll
    for (int j = 0; j < 8; ++j) a0[j] += (float)v[j];
  }
#pragma unroll
  for (int j = 0; j < 8; ++j) a0[j] = (a0[j] + a1[j]) + (a2[j] + a3[j]);
  return a0;
}

// ======== layer-1 aggregation ========
__global__ __launch_bounds__(512) void agg1_kernel(
    const int* __restrict__ rowptr, const unsigned short* __restrict__ csr,
    const h16* __restrict__ x, const float* __restrict__ nin,
    const float* __restrict__ bias, const float* __restrict__ nout,
    half8* __restrict__ y, float* __restrict__ out, int N) {
  int t = blockIdx.x * 512 + threadIdx.x;
  int node = t >> 3;
  if (node >= N) return;
  int lane = t & 7;
  float8 acc = gather_row(rowptr, csr, reinterpret_cast<const half8*>(x), node, lane);
  const float s = nin[node];
  const float no = nout[node];
  float8 h;
  half8 hv;
#pragma unroll
  for (int j = 0; j < 8; ++j) {
    h[j] = fmaxf(acc[j] * s + bias[lane * 8 + j], 0.f);
    hv[j] = (h16)(h[j] * no);
  }
  size_t off = (size_t)node * 64 + lane * 8;
  *reinterpret_cast<float4*>(out + off)     = make_float4(h[0], h[1], h[2], h[3]);
  *reinterpret_cast<float4*>(out + off + 4) = make_float4(h[4], h[5], h[6], h[7]);
  y[(size_t)node * 8 + lane] = hv;
}

// ======== fused layer (2,3): gather -> nin-scale -> @W -> relu/max/out [, fp16 table] ========
template <bool WRITEC>
__global__ __launch_bounds__(512) void fused_layer(
    const int* __restrict__ rowptr, const unsigned short* __restrict__ csr,
    const h16* __restrict__ x, const float* __restrict__ W,
    const float* __restrict__ nin, const float* __restrict__ bias,
    const float* __restrict__ nout,
    half4* __restrict__ C, float* __restrict__ out, int N) {
  __shared__ float sA[64][68];
  __shared__ float sB[64][64];
  const int t = threadIdx.x;
  const int row0 = blockIdx.x * 64;

  for (int i = t * 4; i < 64 * 64; i += 512 * 4)
    *reinterpret_cast<float4*>(&sB[0][0] + i) = *reinterpret_cast<const float4*>(W + i);

  {
    const int node = t >> 3, lane = t & 7;
    const int g = row0 + node;
    float8 acc = 0.f;
    float s = 0.f;
    if (g < N) {
      acc = gather_row(rowptr, csr, reinterpret_cast<const half8*>(x), g, lane);
      s = nin[g];
    }
    *reinterpret_cast<float4*>(&sA[node][lane * 8]) =
        make_float4(acc[0] * s, acc[1] * s, acc[2] * s, acc[3] * s);
    *reinterpret_cast<float4*>(&sA[node][lane * 8 + 4]) =
        make_float4(acc[4] * s, acc[5] * s, acc[6] * s, acc[7] * s);
  }
  __syncthreads();

  const int tx = t & 15;
  const int ry = t >> 4;
  const int r0 = 2 * ry, r1 = r0 + 1;
  float4 a0 = make_float4(0.f, 0.f, 0.f, 0.f);
  float4 a1 = make_float4(0.f, 0.f, 0.f, 0.f);
#pragma unroll 8
  for (int k = 0; k < 64; ++k) {
    float x0 = sA[r0][k], x1 = sA[r1][k];
    float4 b = *reinterpret_cast<float4*>(&sB[k][tx * 4]);
    a0.x += x0 * b.x; a0.y += x0 * b.y; a0.z += x0 * b.z; a0.w += x0 * b.w;
    a1.x += x1 * b.x; a1.y += x1 * b.y; a1.z += x1 * b.z; a1.w += x1 * b.w;
  }

  const float4 bb = *reinterpret_cast<const float4*>(bias + tx * 4);
#pragma unroll
  for (int rr = 0; rr < 2; ++rr) {
    const int gr = row0 + (rr ? r1 : r0);
    if (gr >= N) continue;
    float4 v = rr ? a1 : a0;
    v.x = fmaxf(v.x + bb.x, 0.f);
    v.y = fmaxf(v.y + bb.y, 0.f);
    v.z = fmaxf(v.z + bb.z, 0.f);
    v.w = fmaxf(v.w + bb.w, 0.f);
    size_t off = (size_t)gr * 64 + tx * 4;
    float4 o = *reinterpret_cast<float4*>(out + off);
    o.x = fmaxf(o.x, v.x);
    o.y = fmaxf(o.y, v.y);
    o.z = fmaxf(o.z, v.z);
    o.w = fmaxf(o.w, v.w);
    *reinterpret_cast<float4*>(out + off) = o;
    if (WRITEC) {
      float no = nout[gr];
      half4 hv;
      hv.x = (h16)(v.x * no); hv.y = (h16)(v.y * no);
      hv.z = (h16)(v.z * no); hv.w = (h16)(v.w * no);
      C[(size_t)gr * 16 + tx] = hv;
    }
  }
}

extern "C" void kernel_launch(void* const* d_in, const int* in_sizes, int n_in,
                              void* d_out, int out_size, void* d_ws, size_t ws_size,
                              hipStream_t stream) {
  const float* feat = (const float*)d_in[0];
  const int* src    = (const int*)d_in[1];
  const int* dst    = (const int*)d_in[2];
  const float* W1   = (const float*)d_in[3];
  const float* b1   = (const float*)d_in[4];
  const float* W2   = (const float*)d_in[5];
  const float* b2   = (const float*)d_in[6];
  const float* W3   = (const float*)d_in[7];
  const float* b3   = (const float*)d_in[8];
  float* out = (float*)d_out;

  const int N = in_sizes[0] / 128;
  const int E = in_sizes[1];

  // ---- workspace layout (no aliasing; ws is ~268 MB) ----
  char* p = (char*)d_ws;
  float* nout       = (float*)p;     p += (size_t)N * 4;
  float* nin        = (float*)p;     p += (size_t)N * 4;
  int*   rowptr     = (int*)p;       p += ((size_t)N + 8) * 4;     // segment-local
  int*   rowptr_abs = (int*)p;       p += ((size_t)N + 8) * 4;     // absolute
  int*   bsums      = (int*)p;       p += 1024 * 4;
  int*   gcur       = (int*)p;       p += 64 * 4;                  // 16 bucket cursors
  unsigned short* csr = (unsigned short*)p;  p += (((size_t)E + 8) & ~7) * 2;
  p = (char*)(((uintptr_t)p + 15) & ~(uintptr_t)15);
  h16*   bufAh = (h16*)p;            p += (size_t)N * 64 * 2;
  h16*   bufBh = (h16*)p;            p += (size_t)N * 64 * 2;
  p = (char*)(((uintptr_t)p + 15) & ~(uintptr_t)15);
  int*   partial = (int*)p;          p += (size_t)RANGES * PPR * HWORDS * 4;  // 13.1 MB
  p = (char*)(((uintptr_t)p + 15) & ~(uintptr_t)15);
  unsigned int* dbucket = (unsigned int*)p;  p += (size_t)RANGES * E * 4;     // 27.2 MB
  unsigned short* sbucket = (unsigned short*)p; p += (size_t)RANGES * E * 2;  // 13.6 MB

  const int ngemm = (N + 127) / 128;

  // ---- bucket -> hist -> reduce -> fill(+gemm1 overlap) ----
  hipMemsetAsync(gcur, 0, 16 * sizeof(int), stream);
  bucket_kernel<<<NBUCK, HTHREADS, 0, stream>>>(src, dst, dbucket, sbucket, gcur, E);
  hist_kernel<<<NFILL, HTHREADS, 0, stream>>>(dbucket, sbucket, gcur, partial, E);
  reduce_norm_scan1<<<NSEG, 256, 0, stream>>>(partial, nout, nin, rowptr, bsums, N);
  fill_gemm_kernel<<<NFILL + ngemm, HTHREADS, 0, stream>>>(
      dbucket, gcur, rowptr, bsums, partial, rowptr_abs, csr,
      feat, W1, nout, (half4*)bufAh, N, E);

  const int gemm_blocks = (N + 63) / 64;
  const int agg1_blocks = (int)(((size_t)N * 8 + 511) / 512);

  // ---- layer 1 aggregation ----
  agg1_kernel<<<agg1_blocks, 512, 0, stream>>>(rowptr_abs, csr, bufAh, nin, b1, nout,
                                               (half8*)bufBh, out, N);
  // ---- layer 2 ----
  fused_layer<true><<<gemm_blocks, 512, 0, stream>>>(rowptr_abs, csr, bufBh, W2, nin, b2, nout,
                                                     (half4*)bufAh, out, N);
  // ---- layer 3 ----
  fused_layer<false><<<gemm_blocks, 512, 0, stream>>>(rowptr_abs, csr, bufAh, W3, nin, b3, nullptr,
                                                      nullptr, out, N);
}

// Round 13
// 147.354 us; speedup vs baseline: 1.0745x; 1.0745x over previous
//
#include <hip/hip_runtime.h>

typedef _Float16 h16;
typedef __attribute__((ext_vector_type(4))) _Float16 half4;
typedef __attribute__((ext_vector_type(8))) _Float16 half8;
typedef __attribute__((ext_vector_type(8))) float float8;

#define RANGES 4
#define PPR    64            // chunks per range -> 256 blocks for hist/fill
#define HTHREADS 1024
#define BINS   12800         // nodes per range: 4*12800 = 51200 >= 50000
#define HALF   (BINS / 2)    // packed words per histogram (odeg or ideg)
#define HWORDS (BINS)        // words per partial: HALF odeg + HALF ideg
#define NSEG   100           // 512-node scan segments (51200/512)
#define NFILL  (RANGES * PPR)
#define SMEMB  (BINS * 4 + 512)   // 51712 B: fill cursors + top scan (max phase)

// ======== histogram: 16-bit-packed LDS counters, per-(range,chunk) partials ========
__global__ __launch_bounds__(HTHREADS) void hist_kernel(const int* __restrict__ src,
                                                        const int* __restrict__ dst,
                                                        int* __restrict__ partial, int E) {
  __shared__ int h[HWORDS];  // 51.2 KB
  const int r = blockIdx.x >> 6;   // range 0..3
  const int c = blockIdx.x & 63;   // chunk
  for (int i = threadIdx.x; i < HWORDS; i += HTHREADS) h[i] = 0;
  __syncthreads();
  const int lo = r * BINS;
  const int chunk = (E + PPR - 1) / PPR;
  const int e0 = c * chunk;
  const int e1 = min(E, e0 + chunk);
  for (int e = e0 + threadIdx.x; e < e1; e += HTHREADS) {
    int s = src[e] - lo;
    if ((unsigned)s < (unsigned)BINS) atomicAdd(&h[s >> 1], 1 << ((s & 1) * 16));
    int d = dst[e] - lo;
    if ((unsigned)d < (unsigned)BINS) atomicAdd(&h[HALF + (d >> 1)], 1 << ((d & 1) * 16));
  }
  __syncthreads();
  int* op = partial + (size_t)blockIdx.x * HWORDS;
  for (int i = threadIdx.x; i < HWORDS; i += HTHREADS) op[i] = h[i];
}

// ======== reduce partials -> norms; in-place chunk-prefix; 512-node segment scan ========
__global__ __launch_bounds__(256) void reduce_norm_scan1(
    int* __restrict__ partial, float* __restrict__ nout, float* __restrict__ nin,
    int* __restrict__ rowptr, int* __restrict__ bsums, int N) {
  __shared__ int s[256];
  const int j = blockIdx.x * 256 + threadIdx.x;    // packed word id, < 25600
  const int r = j / HALF;                          // range 0..3
  const int w = j % HALF;
  int* base = partial + (size_t)(r * PPR) * HWORDS;
  int sumO = 0, runI = 0;
#pragma unroll 8
  for (int p = 0; p < PPR; ++p) {
    sumO += base[(size_t)p * HWORDS + w];
    int vI = base[(size_t)p * HWORDS + HALF + w];
    base[(size_t)p * HWORDS + HALF + w] = runI;    // exclusive chunk-prefix (packed; no carry)
    runI += vI;
  }
  const int od0 = sumO & 0xFFFF, od1 = (sumO >> 16) & 0xFFFF;
  const int id0 = runI & 0xFFFF, id1 = (runI >> 16) & 0xFFFF;
  const int n0 = 2 * j, n1 = n0 + 1;
  if (n0 < N) {
    nout[n0] = od0 > 0 ? rsqrtf((float)od0) : 0.f;
    nin[n0]  = id0 > 0 ? rsqrtf((float)id0) : 0.f;
  }
  if (n1 < N) {
    nout[n1] = od1 > 0 ? rsqrtf((float)od1) : 0.f;
    nin[n1]  = id1 > 0 ? rsqrtf((float)id1) : 0.f;
  }
  const int local = id0 + id1;
  int v = local;
  s[threadIdx.x] = v;
  __syncthreads();
#pragma unroll
  for (int off = 1; off < 256; off <<= 1) {
    int tv = 0;
    if (threadIdx.x >= off) tv = s[threadIdx.x - off];
    __syncthreads();
    if (threadIdx.x >= off) s[threadIdx.x] += tv;
    __syncthreads();
  }
  const int excl = s[threadIdx.x] - v;              // segment-local exclusive start
  if (n0 < N) rowptr[n0] = excl;
  if (n1 < N) rowptr[n1] = excl + id0;
  if (threadIdx.x == 255) bsums[blockIdx.x] = s[255];
}

// ======== heterogeneous: blocks [0,256) CSR-fill; blocks [256,..) gemm1 ========
// fill: u16 csr entries via LDS cursors; folds top-scan + abs-rowptr write.
// gemm1: bufAh = half((feat @ W1) * nout), 128-row tiles, K=128 in 2 chunks.
__global__ __launch_bounds__(HTHREADS) void fill_gemm_kernel(
    const int* __restrict__ src, const int* __restrict__ dst,
    const int* __restrict__ rowptr, const int* __restrict__ bsums,
    const int* __restrict__ partial, int* __restrict__ rowptr_abs,
    unsigned short* __restrict__ csr,
    const float* __restrict__ feat, const float* __restrict__ W1,
    const float* __restrict__ nout, half4* __restrict__ bufAh,
    int N, int E) {
  __shared__ __align__(16) char smem[SMEMB];
  const int tid = threadIdx.x;

  if (blockIdx.x < NFILL) {
    // ---------------- fill ----------------
    int* cur = (int*)smem;                  // [BINS] absolute cursors (51.2 KB)
    int* top = (int*)(smem + BINS * 4);     // [128] scanned segment sums
    const int r = blockIdx.x & 3;    // range (spread across XCDs via bid%8 pairs)
    const int c = blockIdx.x >> 2;   // chunk 0..63
    if (tid < 128) top[tid] = (tid < NSEG) ? bsums[tid] : 0;
    __syncthreads();
#pragma unroll
    for (int off = 1; off < 128; off <<= 1) {
      int v = 0;
      if (tid < 128 && tid >= off) v = top[tid - off];
      __syncthreads();
      if (tid < 128 && tid >= off) top[tid] += v;
      __syncthreads();
    }
    const int lo = r * BINS;
    const int* pf = partial + (size_t)(r * PPR + c) * HWORDS + HALF;
    for (int n = tid; n < BINS; n += HTHREADS) {
      int g = lo + n;
      int rp = 0;
      if (g < N) {
        int seg = g >> 9;
        rp = rowptr[g] + (seg ? top[seg - 1] : 0);     // absolute row start
        if (c == 0) rowptr_abs[g] = rp;
      }
      int pw = pf[n >> 1];
      cur[n] = rp + ((pw >> ((n & 1) * 16)) & 0xFFFF);
    }
    if (blockIdx.x == 0 && tid == 0) rowptr_abs[N] = E;
    __syncthreads();
    const int chunk = (E + PPR - 1) / PPR;
    const int e0 = c * chunk;
    const int e1 = min(E, e0 + chunk);
    for (int e = e0 + tid; e < e1; e += HTHREADS) {
      int d = dst[e] - lo;
      if ((unsigned)d < (unsigned)BINS) {
        int pos = atomicAdd(&cur[d], 1);
        csr[pos] = (unsigned short)src[e];
      }
    }
  } else {
    // ---------------- gemm1 (128-row tile, 1024 threads) ----------------
    float* sA = (float*)smem;                   // [128][68]
    float* sB = (float*)(smem + 128 * 68 * 4);  // [64][64]
    const int tile = blockIdx.x - NFILL;
    const int row0 = tile << 7;
    const int ry = tid >> 4;                // 0..63 -> rows 2ry, 2ry+1
    const int tx = tid & 15;
    const int r0 = 2 * ry, r1 = r0 + 1;
    float4 acc0 = make_float4(0.f, 0.f, 0.f, 0.f);
    float4 acc1 = make_float4(0.f, 0.f, 0.f, 0.f);
#pragma unroll
    for (int kc = 0; kc < 2; ++kc) {
      __syncthreads();
      for (int i = tid * 4; i < 128 * 64; i += HTHREADS * 4) {
        int rr = i >> 6, cc = i & 63;
        int gr = row0 + rr;
        float4 v = make_float4(0.f, 0.f, 0.f, 0.f);
        if (gr < N) v = *reinterpret_cast<const float4*>(feat + (size_t)gr * 128 + kc * 64 + cc);
        *reinterpret_cast<float4*>(sA + rr * 68 + cc) = v;
      }
      {
        int i = tid * 4;
        int rr = i >> 6, cc = i & 63;
        *reinterpret_cast<float4*>(sB + rr * 64 + cc) =
            *reinterpret_cast<const float4*>(W1 + (size_t)(kc * 64 + rr) * 64 + cc);
      }
      __syncthreads();
#pragma unroll 8
      for (int k = 0; k < 64; ++k) {
        float a0 = sA[r0 * 68 + k], a1 = sA[r1 * 68 + k];
        float4 b = *reinterpret_cast<float4*>(sB + k * 64 + tx * 4);
        acc0.x += a0 * b.x; acc0.y += a0 * b.y; acc0.z += a0 * b.z; acc0.w += a0 * b.w;
        acc1.x += a1 * b.x; acc1.y += a1 * b.y; acc1.z += a1 * b.z; acc1.w += a1 * b.w;
      }
    }
#pragma unroll
    for (int rr = 0; rr < 2; ++rr) {
      const int gr = row0 + (rr ? r1 : r0);
      if (gr >= N) continue;
      float4 v = rr ? acc1 : acc0;
      float no = nout[gr];
      half4 hv;
      hv.x = (h16)(v.x * no); hv.y = (h16)(v.y * no);
      hv.z = (h16)(v.z * no); hv.w = (h16)(v.w * no);
      bufAh[(size_t)gr * 16 + tx] = hv;
    }
  }
}

// ======== shared gather core: 8 lanes/node, half8 (16B) loads, 8-way MLP unroll ========
__device__ __forceinline__ float8 gather_row(const int* __restrict__ rowptr,
                                             const unsigned short* __restrict__ csr,
                                             const half8* __restrict__ xv,
                                             int node, int lane) {
  const int b = rowptr[node], e = rowptr[node + 1];
  float8 a0 = 0.f, a1 = 0.f, a2 = 0.f, a3 = 0.f;
  int i = b;
  for (; i + 8 <= e; i += 8) {
    int s0 = csr[i + 0], s1 = csr[i + 1], s2 = csr[i + 2], s3 = csr[i + 3];
    int s4 = csr[i + 4], s5 = csr[i + 5], s6 = csr[i + 6], s7 = csr[i + 7];
    half8 v0 = xv[(size_t)s0 * 8 + lane];
    half8 v1 = xv[(size_t)s1 * 8 + lane];
    half8 v2 = xv[(size_t)s2 * 8 + lane];
    half8 v3 = xv[(size_t)s3 * 8 + lane];
    half8 v4 = xv[(size_t)s4 * 8 + lane];
    half8 v5 = xv[(size_t)s5 * 8 + lane];
    half8 v6 = xv[(size_t)s6 * 8 + lane];
    half8 v7 = xv[(size_t)s7 * 8 + lane];
#pragma unroll
    for (int j = 0; j < 8; ++j) {
      a0[j] += (float)v0[j]; a1[j] += (float)v1[j];
      a2[j] += (float)v2[j]; a3[j] += (float)v3[j];
      a0[j] += (float)v4[j]; a1[j] += (float)v5[j];
      a2[j] += (float)v6[j]; a3[j] += (float)v7[j];
    }
  }
  for (; i + 4 <= e; i += 4) {
    int s0 = csr[i + 0], s1 = csr[i + 1], s2 = csr[i + 2], s3 = csr[i + 3];
    half8 v0 = xv[(size_t)s0 * 8 + lane];
    half8 v1 = xv[(size_t)s1 * 8 + lane];
    half8 v2 = xv[(size_t)s2 * 8 + lane];
    half8 v3 = xv[(size_t)s3 * 8 + lane];
#pragma unroll
    for (int j = 0; j < 8; ++j) {
      a0[j] += (float)v0[j]; a1[j] += (float)v1[j];
      a2[j] += (float)v2[j]; a3[j] += (float)v3[j];
    }
  }
  for (; i < e; ++i) {
    int s = csr[i];
    half8 v = xv[(size_t)s * 8 + lane];
#pragma unroll
    for (int j = 0; j < 8; ++j) a0[j] += (float)v[j];
  }
#pragma unroll
  for (int j = 0; j < 8; ++j) a0[j] = (a0[j] + a1[j]) + (a2[j] + a3[j]);
  return a0;
}

// ======== layer-1 aggregation ========
__global__ __launch_bounds__(512) void agg1_kernel(
    const int* __restrict__ rowptr, const unsigned short* __restrict__ csr,
    const h16* __restrict__ x, const float* __restrict__ nin,
    const float* __restrict__ bias, const float* __restrict__ nout,
    half8* __restrict__ y, float* __restrict__ out, int N) {
  int t = blockIdx.x * 512 + threadIdx.x;
  int node = t >> 3;
  if (node >= N) return;
  int lane = t & 7;
  float8 acc = gather_row(rowptr, csr, reinterpret_cast<const half8*>(x), node, lane);
  const float s = nin[node];
  const float no = nout[node];
  float8 h;
  half8 hv;
#pragma unroll
  for (int j = 0; j < 8; ++j) {
    h[j] = fmaxf(acc[j] * s + bias[lane * 8 + j], 0.f);
    hv[j] = (h16)(h[j] * no);
  }
  size_t off = (size_t)node * 64 + lane * 8;
  *reinterpret_cast<float4*>(out + off)     = make_float4(h[0], h[1], h[2], h[3]);
  *reinterpret_cast<float4*>(out + off + 4) = make_float4(h[4], h[5], h[6], h[7]);
  y[(size_t)node * 8 + lane] = hv;
}

// ======== fused layer (2,3): gather -> nin-scale -> @W -> relu/max/out [, fp16 table] ========
template <bool WRITEC>
__global__ __launch_bounds__(512) void fused_layer(
    const int* __restrict__ rowptr, const unsigned short* __restrict__ csr,
    const h16* __restrict__ x, const float* __restrict__ W,
    const float* __restrict__ nin, const float* __restrict__ bias,
    const float* __restrict__ nout,
    half4* __restrict__ C, float* __restrict__ out, int N) {
  __shared__ float sA[64][68];
  __shared__ float sB[64][64];
  const int t = threadIdx.x;
  const int row0 = blockIdx.x * 64;

  for (int i = t * 4; i < 64 * 64; i += 512 * 4)
    *reinterpret_cast<float4*>(&sB[0][0] + i) = *reinterpret_cast<const float4*>(W + i);

  {
    const int node = t >> 3, lane = t & 7;
    const int g = row0 + node;
    float8 acc = 0.f;
    float s = 0.f;
    if (g < N) {
      acc = gather_row(rowptr, csr, reinterpret_cast<const half8*>(x), g, lane);
      s = nin[g];
    }
    *reinterpret_cast<float4*>(&sA[node][lane * 8]) =
        make_float4(acc[0] * s, acc[1] * s, acc[2] * s, acc[3] * s);
    *reinterpret_cast<float4*>(&sA[node][lane * 8 + 4]) =
        make_float4(acc[4] * s, acc[5] * s, acc[6] * s, acc[7] * s);
  }
  __syncthreads();

  const int tx = t & 15;
  const int ry = t >> 4;
  const int r0 = 2 * ry, r1 = r0 + 1;
  float4 a0 = make_float4(0.f, 0.f, 0.f, 0.f);
  float4 a1 = make_float4(0.f, 0.f, 0.f, 0.f);
#pragma unroll 8
  for (int k = 0; k < 64; ++k) {
    float x0 = sA[r0][k], x1 = sA[r1][k];
    float4 b = *reinterpret_cast<float4*>(&sB[k][tx * 4]);
    a0.x += x0 * b.x; a0.y += x0 * b.y; a0.z += x0 * b.z; a0.w += x0 * b.w;
    a1.x += x1 * b.x; a1.y += x1 * b.y; a1.z += x1 * b.z; a1.w += x1 * b.w;
  }

  const float4 bb = *reinterpret_cast<const float4*>(bias + tx * 4);
#pragma unroll
  for (int rr = 0; rr < 2; ++rr) {
    const int gr = row0 + (rr ? r1 : r0);
    if (gr >= N) continue;
    float4 v = rr ? a1 : a0;
    v.x = fmaxf(v.x + bb.x, 0.f);
    v.y = fmaxf(v.y + bb.y, 0.f);
    v.z = fmaxf(v.z + bb.z, 0.f);
    v.w = fmaxf(v.w + bb.w, 0.f);
    size_t off = (size_t)gr * 64 + tx * 4;
    float4 o = *reinterpret_cast<float4*>(out + off);
    o.x = fmaxf(o.x, v.x);
    o.y = fmaxf(o.y, v.y);
    o.z = fmaxf(o.z, v.z);
    o.w = fmaxf(o.w, v.w);
    *reinterpret_cast<float4*>(out + off) = o;
    if (WRITEC) {
      float no = nout[gr];
      half4 hv;
      hv.x = (h16)(v.x * no); hv.y = (h16)(v.y * no);
      hv.z = (h16)(v.z * no); hv.w = (h16)(v.w * no);
      C[(size_t)gr * 16 + tx] = hv;
    }
  }
}

extern "C" void kernel_launch(void* const* d_in, const int* in_sizes, int n_in,
                              void* d_out, int out_size, void* d_ws, size_t ws_size,
                              hipStream_t stream) {
  const float* feat = (const float*)d_in[0];
  const int* src    = (const int*)d_in[1];
  const int* dst    = (const int*)d_in[2];
  const float* W1   = (const float*)d_in[3];
  const float* b1   = (const float*)d_in[4];
  const float* W2   = (const float*)d_in[5];
  const float* b2   = (const float*)d_in[6];
  const float* W3   = (const float*)d_in[7];
  const float* b3   = (const float*)d_in[8];
  float* out = (float*)d_out;

  const int N = in_sizes[0] / 128;
  const int E = in_sizes[1];

  // ---- workspace layout (no aliasing; ws is ~268 MB) ----
  char* p = (char*)d_ws;
  float* nout       = (float*)p;     p += (size_t)N * 4;
  float* nin        = (float*)p;     p += (size_t)N * 4;
  int*   rowptr     = (int*)p;       p += ((size_t)N + 8) * 4;     // segment-local
  int*   rowptr_abs = (int*)p;       p += ((size_t)N + 8) * 4;     // absolute
  int*   bsums      = (int*)p;       p += 1024 * 4;
  unsigned short* csr = (unsigned short*)p;  p += (((size_t)E + 8) & ~7) * 2;
  p = (char*)(((uintptr_t)p + 15) & ~(uintptr_t)15);
  h16*   bufAh = (h16*)p;            p += (size_t)N * 64 * 2;
  h16*   bufBh = (h16*)p;            p += (size_t)N * 64 * 2;
  p = (char*)(((uintptr_t)p + 15) & ~(uintptr_t)15);
  int*   partial = (int*)p;          p += (size_t)RANGES * PPR * HWORDS * 4;  // 13.1 MB

  const int ngemm = (N + 127) / 128;

  // ---- CSR build + layer-1 GEMM (gemm1 overlapped with fill) ----
  hist_kernel<<<NFILL, HTHREADS, 0, stream>>>(src, dst, partial, E);
  reduce_norm_scan1<<<NSEG, 256, 0, stream>>>(partial, nout, nin, rowptr, bsums, N);
  fill_gemm_kernel<<<NFILL + ngemm, HTHREADS, 0, stream>>>(
      src, dst, rowptr, bsums, partial, rowptr_abs, csr,
      feat, W1, nout, (half4*)bufAh, N, E);

  const int gemm_blocks = (N + 63) / 64;
  const int agg1_blocks = (int)(((size_t)N * 8 + 511) / 512);

  // ---- layer 1 aggregation ----
  agg1_kernel<<<agg1_blocks, 512, 0, stream>>>(rowptr_abs, csr, bufAh, nin, b1, nout,
                                               (half8*)bufBh, out, N);
  // ---- layer 2 ----
  fused_layer<true><<<gemm_blocks, 512, 0, stream>>>(rowptr_abs, csr, bufBh, W2, nin, b2, nout,
                                                     (half4*)bufAh, out, N);
  // ---- layer 3 ----
  fused_layer<false><<<gemm_blocks, 512, 0, stream>>>(rowptr_abs, csr, bufAh, W3, nin, b3, nullptr,
                                                      nullptr, out, N);
}